// Round 1
// baseline (524.309 us; speedup 1.0000x reference)
//
#include <hip/hip_runtime.h>

// SpatialEncoding: out[src,dst] = b[min(path_len,5)-1], last-write-wins in p order.
//
// Strategy: 32-bit key = ((p+1)<<3) | clamped  (p+1 <= 8e6 < 2^23, clamped < 8).
// atomicMax(key) into out-as-uint32 => highest p wins == numpy last-write-wins.
// Key 0 == "never written" (since p+1 >= 1). Decode pass maps key -> b[key&7].

__global__ void se_scatter_kernel(const int* __restrict__ src_idx,
                                  const int* __restrict__ dst_idx,
                                  const int* __restrict__ path_len,
                                  unsigned int* __restrict__ out_keys,
                                  int P, int n) {
    int p = blockIdx.x * blockDim.x + threadIdx.x;
    if (p >= P) return;
    int len = path_len[p];
    int clamped = (len < 5 ? len : 5) - 1;               // in [0,4]
    unsigned int key = ((unsigned int)(p + 1) << 3) | (unsigned int)clamped;
    size_t cell = (size_t)src_idx[p] * (size_t)n + (size_t)dst_idx[p];
    atomicMax(out_keys + cell, key);
}

__global__ void se_decode_kernel(unsigned int* __restrict__ out_keys,
                                 const float* __restrict__ b,
                                 long long total) {
    long long i4 = (long long)(blockIdx.x) * blockDim.x + threadIdx.x;
    long long base = i4 * 4;
    if (base >= total) return;

    float b0 = b[0], b1 = b[1], b2 = b[2], b3 = b[3], b4 = b[4];

    if (base + 3 < total) {
        uint4 k = *reinterpret_cast<const uint4*>(out_keys + base);
        float4 v;
        {
            unsigned c = k.x & 7u;
            float t = (c == 0u) ? b0 : (c == 1u) ? b1 : (c == 2u) ? b2 : (c == 3u) ? b3 : b4;
            v.x = k.x ? t : 0.0f;
        }
        {
            unsigned c = k.y & 7u;
            float t = (c == 0u) ? b0 : (c == 1u) ? b1 : (c == 2u) ? b2 : (c == 3u) ? b3 : b4;
            v.y = k.y ? t : 0.0f;
        }
        {
            unsigned c = k.z & 7u;
            float t = (c == 0u) ? b0 : (c == 1u) ? b1 : (c == 2u) ? b2 : (c == 3u) ? b3 : b4;
            v.z = k.z ? t : 0.0f;
        }
        {
            unsigned c = k.w & 7u;
            float t = (c == 0u) ? b0 : (c == 1u) ? b1 : (c == 2u) ? b2 : (c == 3u) ? b3 : b4;
            v.w = k.w ? t : 0.0f;
        }
        *reinterpret_cast<float4*>(out_keys + base) = *reinterpret_cast<float4*>(&v);
    } else {
        for (long long i = base; i < total; ++i) {
            unsigned k = out_keys[i];
            unsigned c = k & 7u;
            float t = (c == 0u) ? b0 : (c == 1u) ? b1 : (c == 2u) ? b2 : (c == 3u) ? b3 : b4;
            float v = k ? t : 0.0f;
            *reinterpret_cast<float*>(out_keys + i) = v;
        }
    }
}

extern "C" void kernel_launch(void* const* d_in, const int* in_sizes, int n_in,
                              void* d_out, int out_size, void* d_ws, size_t ws_size,
                              hipStream_t stream) {
    // inputs: 0=x [N*128 f32], 1=b [5 f32], 2=src_idx [P i32], 3=dst_idx [P i32], 4=path_len [P i32]
    const float* b        = (const float*)d_in[1];
    const int*   src_idx  = (const int*)d_in[2];
    const int*   dst_idx  = (const int*)d_in[3];
    const int*   path_len = (const int*)d_in[4];
    int P = in_sizes[2];
    int n = in_sizes[0] / 128;   // N = 6000

    unsigned int* out_keys = (unsigned int*)d_out;

    // 1) zero the output (keys start at 0 == untouched)
    hipMemsetAsync(d_out, 0, (size_t)out_size * sizeof(float), stream);

    // 2) ordered scatter via atomicMax on encoded keys
    {
        int block = 256;
        int grid = (P + block - 1) / block;
        se_scatter_kernel<<<grid, block, 0, stream>>>(src_idx, dst_idx, path_len,
                                                      out_keys, P, n);
    }

    // 3) decode keys -> float values in place (x4 vectorized)
    {
        long long total = (long long)out_size;
        long long n4 = (total + 3) / 4;
        int block = 256;
        long long grid = (n4 + block - 1) / block;
        se_decode_kernel<<<(int)grid, block, 0, stream>>>(out_keys, b, total);
    }
}